// Round 24
// baseline (181.023 us; speedup 1.0000x reference)
//
#include <hip/hip_runtime.h>
#include <hip/hip_bf16.h>
#include <cstdint>

#define NN 8192
#define EE 128
#define AA 8
#define QSCALE 0.08838834764831845f   // 1/sqrt(128)
#define NKVS 8                         // KV splits
#define KVLEN (NN / NKVS)              // 1024 cols per split
#define NIT (KVLEN / 64)               // 16 chunks
#define NW (NN / 64)                   // 128 mask words per row
#define QTILE 256                      // q-rows per attn block (8 waves x 32)

typedef __attribute__((ext_vector_type(8))) short bf16x8;
typedef __attribute__((ext_vector_type(16))) float f32x16;
typedef unsigned short u16;
typedef unsigned int u32;
typedef unsigned long long u64;

__device__ __forceinline__ u16 bf16_bits(float x) {
    union { float f; u32 u; } v; v.f = x;
    u32 r = v.u + 0x7fffu + ((v.u >> 16) & 1u);   // RNE
    return (u16)(r >> 16);
}

__device__ __forceinline__ u32 cvtpk_bf16(float lo, float hi) {
    u32 r;
    asm("v_cvt_pk_bf16_f32 %0, %1, %2" : "=v"(r) : "v"(lo), "v"(hi));
    return r;
}

// ---------------------------------------------------------------------------
// Kernel 1 (fused): adjmask + MLP, INTERLEAVED block roles.
// 4608 blocks x 128 thr: b%9==8 -> MLP tile b/9 (512 tiles), else adjmask
// (4096 stream blocks). Interleaving keeps both populations co-resident
// from dispatch #0 (R15's failure: mlp blocks dispatched last + 33KB LDS;
// here LDS=16.5KB -> 9 blocks/CU, and mlp hides in the adj stream stalls).
// Per-path code identical to the R23-measured k_adjmask / k_mlp.
// ---------------------------------------------------------------------------
__global__ __launch_bounds__(128) void k_pre(
    const int* __restrict__ adj, u64* __restrict__ msk,
    const float* __restrict__ state,
    const float* __restrict__ w1, const float* __restrict__ b1,
    const float* __restrict__ w2, const float* __restrict__ b2,
    const float* __restrict__ wq, const float* __restrict__ wk,
    u16* __restrict__ qb, u16* __restrict__ kb, u16* __restrict__ hT)
{
    __shared__ float st[16][EE + 1];   // 16.5 KB total (adj blocks ignore)
    __shared__ float h1[16][EE + 1];
    const int t = threadIdx.x;
    const u32 b = blockIdx.x;

    if (b % 9u != 8u) {
        // ---- adjmask path: 4096 blocks x 2 waves, grid-stride ballot ----
        const u32 ab     = b - (b + 1) / 9u;        // 0..4095
        const u32 gwave  = (ab * 128 + t) >> 6;     // 8192 waves total
        const u32 nwaves = 8192;
        const int lane   = t & 63;
        const size_t nwords = (size_t)NN * NW;      // 1,048,576
        for (size_t w = (size_t)gwave * 4; w < nwords; w += (size_t)nwaves * 4) {
            u64 bb[4];
            #pragma unroll
            for (int u = 0; u < 4; ++u)
                bb[u] = __ballot(adj[(w + u) * 64 + lane] != 0);
            if (lane == 0) {
                *reinterpret_cast<ulonglong2*>(&msk[w])     = ulonglong2{bb[0], bb[1]};
                *reinterpret_cast<ulonglong2*>(&msk[w + 2]) = ulonglong2{bb[2], bb[3]};
            }
        }
        return;
    }

    // ---- MLP path: tile (b/9) of 512; 16 rows, 2 rows x 8 cols/thread ----
    const int r0b = (int)(b / 9u) * 16;
    const int ec  = (t & 15) * 8;
    const int ra  = (t >> 4) * 2, rb = ra + 1;

    #pragma unroll
    for (int r = 0; r < 16; ++r)
        st[r][t] = state[(size_t)(r0b + r) * EE + t];
    __syncthreads();

    {
        float a0[8], a1[8];
        #pragma unroll
        for (int j = 0; j < 8; ++j) { float bb = b1[ec + j]; a0[j] = bb; a1[j] = bb; }
        for (int s = 0; s < EE; ++s) {
            float x0 = st[ra][s], x1 = st[rb][s];
            const float* wrow = w1 + s * EE + ec;
            #pragma unroll
            for (int j = 0; j < 8; ++j) { float w = wrow[j]; a0[j] = fmaf(x0, w, a0[j]); a1[j] = fmaf(x1, w, a1[j]); }
        }
        __syncthreads();
        #pragma unroll
        for (int j = 0; j < 8; ++j) { h1[ra][ec + j] = fmaxf(a0[j], 0.f); h1[rb][ec + j] = fmaxf(a1[j], 0.f); }
    }
    __syncthreads();

    float hva[8], hvb[8];
    {
        float a0[8], a1[8];
        #pragma unroll
        for (int j = 0; j < 8; ++j) { float bb = b2[ec + j]; a0[j] = bb; a1[j] = bb; }
        for (int s = 0; s < EE; ++s) {
            float x0 = h1[ra][s], x1 = h1[rb][s];
            const float* wrow = w2 + s * EE + ec;
            #pragma unroll
            for (int j = 0; j < 8; ++j) { float w = wrow[j]; a0[j] = fmaf(x0, w, a0[j]); a1[j] = fmaf(x1, w, a1[j]); }
        }
        #pragma unroll
        for (int j = 0; j < 8; ++j) {
            st[ra][ec + j] = a0[j]; st[rb][ec + j] = a1[j];
            hva[j] = a0[j]; hvb[j] = a1[j];
        }
    }
    __syncthreads();

    {
        float q0[8], q1[8], k0[8], k1[8];
        #pragma unroll
        for (int j = 0; j < 8; ++j) { q0[j] = 0.f; q1[j] = 0.f; k0[j] = 0.f; k1[j] = 0.f; }
        for (int s = 0; s < EE; ++s) {
            float x0 = st[ra][s], x1 = st[rb][s];
            const float* wqr = wq + s * EE + ec;
            const float* wkr = wk + s * EE + ec;
            #pragma unroll
            for (int j = 0; j < 8; ++j) {
                float a = wqr[j], bb = wkr[j];
                q0[j] = fmaf(x0, a, q0[j]); q1[j] = fmaf(x1, a, q1[j]);
                k0[j] = fmaf(x0, bb, k0[j]); k1[j] = fmaf(x1, bb, k1[j]);
            }
        }
        bf16x8 vq0, vq1, vk0, vk1;
        #pragma unroll
        for (int j = 0; j < 8; ++j) {
            vq0[j] = (short)bf16_bits(q0[j] * QSCALE);
            vq1[j] = (short)bf16_bits(q1[j] * QSCALE);
            vk0[j] = (short)bf16_bits(k0[j]);
            vk1[j] = (short)bf16_bits(k1[j]);
        }
        *reinterpret_cast<bf16x8*>(qb + (size_t)(r0b + ra) * EE + ec) = vq0;
        *reinterpret_cast<bf16x8*>(qb + (size_t)(r0b + rb) * EE + ec) = vq1;
        *reinterpret_cast<bf16x8*>(kb + (size_t)(r0b + ra) * EE + ec) = vk0;
        *reinterpret_cast<bf16x8*>(kb + (size_t)(r0b + rb) * EE + ec) = vk1;
    }

    #pragma unroll
    for (int j = 0; j < 8; ++j) {
        u32 pack = (u32)bf16_bits(hva[j]) | ((u32)bf16_bits(hvb[j]) << 16);
        *reinterpret_cast<u32*>(hT + (size_t)(ec + j) * NN + r0b + ra) = pack;
    }
}

// ---------------------------------------------------------------------------
// Kernel 2: flash attention, 32x32 swapped QK^T, QTILE=256 (8 waves).
// (R23-measured version, unchanged: rescale-skip included.)
// ---------------------------------------------------------------------------
__global__ __launch_bounds__(512, 2) void k_attn(
    const u16* __restrict__ qb, const u16* __restrict__ kb,
    const u16* __restrict__ hT, const u64* __restrict__ msk,
    _Float16* __restrict__ pacc, float* __restrict__ pm, float* __restrict__ pl)
{
    __shared__ char smem[65536];   // K dbuf 2x16KB @0 | hT dbuf 2x16KB @32768

    const int tid  = threadIdx.x;
    const int wv   = tid >> 6;
    const int lane = tid & 63;
    const int l31  = lane & 31;
    const int hf   = lane >> 5;
    const int qt   = blockIdx.x >> 3;
    const int kvs  = blockIdx.x & 7;
    const int qr0  = qt * QTILE + wv * 32;
    const int kv0  = kvs * KVLEN;

    bf16x8 qf[8];
    #pragma unroll
    for (int s = 0; s < 8; ++s)
        qf[s] = *reinterpret_cast<const bf16x8*>(
            qb + (size_t)(qr0 + l31) * EE + s * 16 + hf * 8);

    f32x16 acc[4];
    #pragma unroll
    for (int et = 0; et < 4; ++et)
        #pragma unroll
        for (int r = 0; r < 16; ++r) acc[et][r] = 0.f;
    float m = -__builtin_inff(), lsum = 0.f;

    const u64* mrow = msk + (size_t)(qr0 + l31) * NW + kvs * NIT;

    const int kr = tid >> 3, kc = (tid & 7) * 16;
    const int hr = tid >> 2, hc = (tid & 3) * 16;
    const int ksw = (kr & 7) << 4, hsw = (hr & 7) << 4;
    bf16x8 kg[2], hg[2];

    auto LOADG = [&](int c0) {
        kg[0] = *reinterpret_cast<const bf16x8*>(kb + (size_t)(c0 + kr) * EE + kc);
        kg[1] = *reinterpret_cast<const bf16x8*>(kb + (size_t)(c0 + kr) * EE + kc + 8);
        hg[0] = *reinterpret_cast<const bf16x8*>(hT + (size_t)hr * NN + c0 + hc);
        hg[1] = *reinterpret_cast<const bf16x8*>(hT + (size_t)hr * NN + c0 + hc + 8);
    };
    auto WLDS = [&](int b) {
        char* kB = smem + b * 16384;
        *reinterpret_cast<bf16x8*>(kB + kr * 256 + ((kc * 2) ^ ksw))      = kg[0];
        *reinterpret_cast<bf16x8*>(kB + kr * 256 + ((kc * 2 + 16) ^ ksw)) = kg[1];
        char* hB = smem + 32768 + b * 16384;
        *reinterpret_cast<bf16x8*>(hB + hr * 128 + ((hc * 2) ^ hsw))      = hg[0];
        *reinterpret_cast<bf16x8*>(hB + hr * 128 + ((hc * 2 + 16) ^ hsw)) = hg[1];
    };

    LOADG(kv0);
    WLDS(0);
    __syncthreads();

    const int rsw = (l31 & 7) << 4;

    for (int cc = 0; cc < NIT; ++cc) {
        if (cc + 1 < NIT) LOADG(kv0 + (cc + 1) * 64);
        const char* kB = smem + (cc & 1) * 16384;
        const char* hB = smem + 32768 + (cc & 1) * 16384;
        const u64 mw = mrow[cc];

        f32x16 sv0, sv1;
        #pragma unroll
        for (int r = 0; r < 16; ++r) { sv0[r] = 0.f; sv1[r] = 0.f; }
        #pragma unroll
        for (int s = 0; s < 8; ++s) {
            bf16x8 a0 = *reinterpret_cast<const bf16x8*>(
                kB + l31 * 256 + ((s * 32 + hf * 16) ^ rsw));
            sv0 = __builtin_amdgcn_mfma_f32_32x32x16_bf16(a0, qf[s], sv0, 0, 0, 0);
            bf16x8 a1 = *reinterpret_cast<const bf16x8*>(
                kB + (32 + l31) * 256 + ((s * 32 + hf * 16) ^ rsw));
            sv1 = __builtin_amdgcn_mfma_f32_32x32x16_bf16(a1, qf[s], sv1, 0, 0, 0);
        }

        float pv[32];
        float rm = -__builtin_inff();
        #pragma unroll
        for (int r = 0; r < 16; ++r) {
            int k0i = (r & 3) + 8 * (r >> 2) + 4 * hf;
            float v0 = ((mw >> k0i) & 1ull) ? sv0[r] : -__builtin_inff();
            float v1 = ((mw >> (k0i + 32)) & 1ull) ? sv1[r] : -__builtin_inff();
            pv[r] = v0; pv[16 + r] = v1;
            rm = fmaxf(rm, fmaxf(v0, v1));
        }
        rm = fmaxf(rm, __shfl_xor(rm, 32));
        const float mn2 = fmaxf(m, rm);
        const float alpha = (mn2 == m) ? 1.f : __expf(m - mn2);
        const bool noresc = __all(mn2 == m);   // wave-uniform: max didn't grow
        m = mn2;

        float rs = 0.f;
        const bool dead = (mn2 == -__builtin_inff());
        #pragma unroll
        for (int i = 0; i < 32; ++i) {
            float p = dead ? 0.f : __expf(pv[i] - mn2);
            pv[i] = p;
            rs += p;
        }
        rs += __shfl_xor(rs, 32);
        lsum = lsum * alpha + rs;

        u32 w[8][2];
        #pragma unroll
        for (int qd = 0; qd < 8; ++qd) {
            int base = 16 * (qd >> 2) + 4 * (qd & 3);
            w[qd][0] = cvtpk_bf16(pv[base], pv[base + 1]);
            w[qd][1] = cvtpk_bf16(pv[base + 2], pv[base + 3]);
        }

        if (!noresc) {   // skip exact-1.0 rescale (64 mults) when wave-uniform
            #pragma unroll
            for (int et = 0; et < 4; ++et)
                #pragma unroll
                for (int r = 0; r < 16; ++r) acc[et][r] *= alpha;
        }

        #pragma unroll
        for (int s = 0; s < 4; ++s) {
            u32 s0 = hf == 0 ? w[2 * s + 1][0] : w[2 * s][0];
            u32 s1 = hf == 0 ? w[2 * s + 1][1] : w[2 * s][1];
            u32 r0 = __shfl_xor(s0, 32);
            u32 r1 = __shfl_xor(s1, 32);
            union { u32 u[4]; bf16x8 v; } b2;
            b2.u[0] = hf == 0 ? w[2 * s][0] : r0;
            b2.u[1] = hf == 0 ? w[2 * s][1] : r1;
            b2.u[2] = hf == 0 ? r0 : w[2 * s + 1][0];
            b2.u[3] = hf == 0 ? r1 : w[2 * s + 1][1];
            #pragma unroll
            for (int et = 0; et < 4; ++et) {
                bf16x8 a2 = *reinterpret_cast<const bf16x8*>(
                    hB + (32 * et + l31) * 128 + ((s * 32 + hf * 16) ^ rsw));
                acc[et] = __builtin_amdgcn_mfma_f32_32x32x16_bf16(a2, b2.v, acc[et], 0, 0, 0);
            }
        }
        if (cc + 1 < NIT) WLDS((cc + 1) & 1);
        __syncthreads();
    }

    const size_t pbase = (size_t)kvs * NN + qr0;
    #pragma unroll
    for (int et = 0; et < 4; ++et)
        #pragma unroll
        for (int r = 0; r < 16; ++r) {
            int e = 32 * et + (r & 3) + 8 * (r >> 2) + 4 * hf;
            pacc[(pbase + l31) * EE + e] = (_Float16)acc[et][r];
        }
    if (hf == 0) {
        pm[pbase + l31] = m;
        pl[pbase + l31] = lsum;
    }
}

// ---------------------------------------------------------------------------
// Kernel 3 (fused): combine the 8 KV-split partials inline, then
// out = relu(agg@wh1+bh1)@wh2 + bh2.  (unchanged)
// ---------------------------------------------------------------------------
__global__ __launch_bounds__(128) void k_head(
    const _Float16* __restrict__ pacc, const float* __restrict__ pm,
    const float* __restrict__ pl,
    const float* __restrict__ wh1, const float* __restrict__ bh1,
    const float* __restrict__ wh2, const float* __restrict__ bh2,
    float* __restrict__ out)
{
    __shared__ float ag[16][EE + 1];
    __shared__ float h2[16][EE + 1];
    __shared__ float eps[16][NKVS];    // per-row ep[p]/L
    const int t  = threadIdx.x;
    const int ec = (t & 15) * 8;
    const int ra = (t >> 4) * 2, rb = ra + 1;
    const int r0b = blockIdx.x * 16;

    if (t < 16) {
        const int row = r0b + t;
        float mp[NKVS], M = -__builtin_inff();
        #pragma unroll
        for (int p = 0; p < NKVS; ++p) { mp[p] = pm[(size_t)p * NN + row]; M = fmaxf(M, mp[p]); }
        float ep[NKVS], L = 0.f;
        #pragma unroll
        for (int p = 0; p < NKVS; ++p) { ep[p] = __expf(mp[p] - M); L += pl[(size_t)p * NN + row] * ep[p]; }
        const float invL = 1.f / L;
        #pragma unroll
        for (int p = 0; p < NKVS; ++p) eps[t][p] = ep[p] * invL;
    }
    __syncthreads();

    #pragma unroll
    for (int r = 0; r < 16; ++r) {
        float s = 0.f;
        #pragma unroll
        for (int p = 0; p < NKVS; ++p)
            s += (float)pacc[((size_t)p * NN + r0b + r) * EE + t] * eps[r][p];
        ag[r][t] = s;
    }
    __syncthreads();

    {
        float a0[8], a1[8];
        #pragma unroll
        for (int j = 0; j < 8; ++j) { float b = bh1[ec + j]; a0[j] = b; a1[j] = b; }
        for (int s = 0; s < EE; ++s) {
            float x0 = ag[ra][s], x1 = ag[rb][s];
            const float* wrow = wh1 + s * EE + ec;
            #pragma unroll
            for (int j = 0; j < 8; ++j) { float w = wrow[j]; a0[j] = fmaf(x0, w, a0[j]); a1[j] = fmaf(x1, w, a1[j]); }
        }
        #pragma unroll
        for (int j = 0; j < 8; ++j) { h2[ra][ec + j] = fmaxf(a0[j], 0.f); h2[rb][ec + j] = fmaxf(a1[j], 0.f); }
    }
    __syncthreads();
    const int r = t >> 3, a = t & 7;
    float o = bh2[a];
    for (int s = 0; s < EE; ++s) o = fmaf(h2[r][s], wh2[s * AA + a], o);
    out[(size_t)(r0b + r) * AA + a] = o;
}

// ---------------------------------------------------------------------------
extern "C" void kernel_launch(void* const* d_in, const int* in_sizes, int n_in,
                              void* d_out, int out_size, void* d_ws, size_t ws_size,
                              hipStream_t stream)
{
    (void)in_sizes; (void)n_in; (void)out_size; (void)ws_size;
    const float* state = (const float*)d_in[0];
    const int*   adj   = (const int*)d_in[1];
    const float* w1  = (const float*)d_in[2];
    const float* b1  = (const float*)d_in[3];
    const float* w2  = (const float*)d_in[4];
    const float* b2  = (const float*)d_in[5];
    const float* wq  = (const float*)d_in[6];
    const float* wk  = (const float*)d_in[7];
    const float* wh1 = (const float*)d_in[8];
    const float* bh1 = (const float*)d_in[9];
    const float* wh2 = (const float*)d_in[10];
    const float* bh2 = (const float*)d_in[11];
    float* out = (float*)d_out;

    char* ws = (char*)d_ws;
    const size_t MB = 1024 * 1024;
    u16*      qb   = (u16*)ws;                       //  0..2 MB
    u16*      kb   = (u16*)(ws + 2 * MB);            //  2..4 MB
    u16*      hT   = (u16*)(ws + 4 * MB);            //  4..6 MB
    u64*      msk  = (u64*)(ws + 10 * MB);           // 10..18 MB
    _Float16* pacc = (_Float16*)(ws + 18 * MB);      // 18..34 MB
    float*    pm   = (float*)(ws + 34 * MB);         // 34..34.25 MB
    float*    pl   = (float*)(ws + 34 * MB + 256 * 1024); // 34.25..34.5 MB

    k_pre  <<<4608, 128, 0, stream>>>(adj, msk, state, w1, b1, w2, b2, wq, wk,
                                      qb, kb, hT);
    k_attn <<<(NN / QTILE) * NKVS, 512, 0, stream>>>(qb, kb, hT, msk, pacc, pm, pl);
    k_head <<<NN / 16, 128, 0, stream>>>(pacc, pm, pl, wh1, bh1, wh2, bh2, out);
}

// Round 25
// 167.462 us; speedup vs baseline: 1.0810x; 1.0810x over previous
//
#include <hip/hip_runtime.h>
#include <hip/hip_bf16.h>
#include <cstdint>

#define NN 8192
#define EE 128
#define AA 8
#define QSCALE 0.08838834764831845f   // 1/sqrt(128)
#define NKVS 8                         // KV splits
#define KVLEN (NN / NKVS)              // 1024 cols per split
#define NIT (KVLEN / 64)               // 16 chunks
#define NW (NN / 64)                   // 128 mask words per row
#define QTILE 256                      // q-rows per attn block (8 waves x 32)

typedef __attribute__((ext_vector_type(8))) short bf16x8;
typedef __attribute__((ext_vector_type(16))) float f32x16;
typedef unsigned short u16;
typedef unsigned int u32;
typedef unsigned long long u64;

__device__ __forceinline__ u16 bf16_bits(float x) {
    union { float f; u32 u; } v; v.f = x;
    u32 r = v.u + 0x7fffu + ((v.u >> 16) & 1u);   // RNE
    return (u16)(r >> 16);
}

__device__ __forceinline__ u32 cvtpk_bf16(float lo, float hi) {
    u32 r;
    asm("v_cvt_pk_bf16_f32 %0, %1, %2" : "=v"(r) : "v"(lo), "v"(hi));
    return r;
}

// ---------------------------------------------------------------------------
// Kernel 0: pack adj (int32 {0,1}, 256MB) into a bitmask (8MB).
// Dedicated streaming kernel (LDS=0, high occupancy): ~5.3 TB/s measured.
// Fusing this read elsewhere regressed THREE times (R15: LDS-occupancy kill;
// R21: uncoalesced per-lane rows; R24: interleaved roles still LDS-capped).
// ---------------------------------------------------------------------------
__global__ __launch_bounds__(256) void k_adjmask(
    const int* __restrict__ adj, u64* __restrict__ msk)
{
    const u32 gwave  = (blockIdx.x * 256 + threadIdx.x) >> 6;
    const u32 nwaves = (gridDim.x * 256) >> 6;
    const int lane   = threadIdx.x & 63;
    const size_t nwords = (size_t)NN * NW;   // 1,048,576
    for (size_t w = (size_t)gwave * 4; w < nwords; w += (size_t)nwaves * 4) {
        u64 b[4];
        #pragma unroll
        for (int u = 0; u < 4; ++u)
            b[u] = __ballot(adj[(w + u) * 64 + lane] != 0);
        if (lane == 0) {
            *reinterpret_cast<ulonglong2*>(&msk[w])     = ulonglong2{b[0], b[1]};
            *reinterpret_cast<ulonglong2*>(&msk[w + 2]) = ulonglong2{b[2], b[3]};
        }
    }
}

// ---------------------------------------------------------------------------
// Kernel 1: h = relu(state@w1+b1)@w2+b2 ; q = (h@wq)/sqrt(E) ; k = h@wk
// (R18/R20/R23 measured version: 16-row tiles, 2 rows x 8 cols/thread.)
// ---------------------------------------------------------------------------
__global__ __launch_bounds__(128) void k_mlp(
    const float* __restrict__ state,
    const float* __restrict__ w1, const float* __restrict__ b1,
    const float* __restrict__ w2, const float* __restrict__ b2,
    const float* __restrict__ wq, const float* __restrict__ wk,
    u16* __restrict__ qb, u16* __restrict__ kb, u16* __restrict__ hT)
{
    __shared__ float st[16][EE + 1];
    __shared__ float h1[16][EE + 1];
    const int t  = threadIdx.x;
    const int ec = (t & 15) * 8;
    const int ra = (t >> 4) * 2, rb = ra + 1;
    const int r0b = blockIdx.x * 16;

    #pragma unroll
    for (int r = 0; r < 16; ++r)
        st[r][t] = state[(size_t)(r0b + r) * EE + t];
    __syncthreads();

    {
        float a0[8], a1[8];
        #pragma unroll
        for (int j = 0; j < 8; ++j) { float b = b1[ec + j]; a0[j] = b; a1[j] = b; }
        for (int s = 0; s < EE; ++s) {
            float x0 = st[ra][s], x1 = st[rb][s];
            const float* wrow = w1 + s * EE + ec;
            #pragma unroll
            for (int j = 0; j < 8; ++j) { float w = wrow[j]; a0[j] = fmaf(x0, w, a0[j]); a1[j] = fmaf(x1, w, a1[j]); }
        }
        __syncthreads();
        #pragma unroll
        for (int j = 0; j < 8; ++j) { h1[ra][ec + j] = fmaxf(a0[j], 0.f); h1[rb][ec + j] = fmaxf(a1[j], 0.f); }
    }
    __syncthreads();

    float hva[8], hvb[8];
    {
        float a0[8], a1[8];
        #pragma unroll
        for (int j = 0; j < 8; ++j) { float b = b2[ec + j]; a0[j] = b; a1[j] = b; }
        for (int s = 0; s < EE; ++s) {
            float x0 = h1[ra][s], x1 = h1[rb][s];
            const float* wrow = w2 + s * EE + ec;
            #pragma unroll
            for (int j = 0; j < 8; ++j) { float w = wrow[j]; a0[j] = fmaf(x0, w, a0[j]); a1[j] = fmaf(x1, w, a1[j]); }
        }
        #pragma unroll
        for (int j = 0; j < 8; ++j) {
            st[ra][ec + j] = a0[j]; st[rb][ec + j] = a1[j];
            hva[j] = a0[j]; hvb[j] = a1[j];
        }
    }
    __syncthreads();

    {
        float q0[8], q1[8], k0[8], k1[8];
        #pragma unroll
        for (int j = 0; j < 8; ++j) { q0[j] = 0.f; q1[j] = 0.f; k0[j] = 0.f; k1[j] = 0.f; }
        for (int s = 0; s < EE; ++s) {
            float x0 = st[ra][s], x1 = st[rb][s];
            const float* wqr = wq + s * EE + ec;
            const float* wkr = wk + s * EE + ec;
            #pragma unroll
            for (int j = 0; j < 8; ++j) {
                float a = wqr[j], b = wkr[j];
                q0[j] = fmaf(x0, a, q0[j]); q1[j] = fmaf(x1, a, q1[j]);
                k0[j] = fmaf(x0, b, k0[j]); k1[j] = fmaf(x1, b, k1[j]);
            }
        }
        bf16x8 vq0, vq1, vk0, vk1;
        #pragma unroll
        for (int j = 0; j < 8; ++j) {
            vq0[j] = (short)bf16_bits(q0[j] * QSCALE);
            vq1[j] = (short)bf16_bits(q1[j] * QSCALE);
            vk0[j] = (short)bf16_bits(k0[j]);
            vk1[j] = (short)bf16_bits(k1[j]);
        }
        *reinterpret_cast<bf16x8*>(qb + (size_t)(r0b + ra) * EE + ec) = vq0;
        *reinterpret_cast<bf16x8*>(qb + (size_t)(r0b + rb) * EE + ec) = vq1;
        *reinterpret_cast<bf16x8*>(kb + (size_t)(r0b + ra) * EE + ec) = vk0;
        *reinterpret_cast<bf16x8*>(kb + (size_t)(r0b + rb) * EE + ec) = vk1;
    }

    #pragma unroll
    for (int j = 0; j < 8; ++j) {
        u32 pack = (u32)bf16_bits(hva[j]) | ((u32)bf16_bits(hvb[j]) << 16);
        *reinterpret_cast<u32*>(hT + (size_t)(ec + j) * NN + r0b + ra) = pack;
    }
}

// ---------------------------------------------------------------------------
// Kernel 2: flash attention, 32x32 swapped QK^T, QTILE=256 (8 waves).
// (R23-measured version: rescale-skip included.)
// ---------------------------------------------------------------------------
__global__ __launch_bounds__(512, 2) void k_attn(
    const u16* __restrict__ qb, const u16* __restrict__ kb,
    const u16* __restrict__ hT, const u64* __restrict__ msk,
    _Float16* __restrict__ pacc, float* __restrict__ pm, float* __restrict__ pl)
{
    __shared__ char smem[65536];   // K dbuf 2x16KB @0 | hT dbuf 2x16KB @32768

    const int tid  = threadIdx.x;
    const int wv   = tid >> 6;
    const int lane = tid & 63;
    const int l31  = lane & 31;
    const int hf   = lane >> 5;
    const int qt   = blockIdx.x >> 3;
    const int kvs  = blockIdx.x & 7;
    const int qr0  = qt * QTILE + wv * 32;
    const int kv0  = kvs * KVLEN;

    bf16x8 qf[8];
    #pragma unroll
    for (int s = 0; s < 8; ++s)
        qf[s] = *reinterpret_cast<const bf16x8*>(
            qb + (size_t)(qr0 + l31) * EE + s * 16 + hf * 8);

    f32x16 acc[4];
    #pragma unroll
    for (int et = 0; et < 4; ++et)
        #pragma unroll
        for (int r = 0; r < 16; ++r) acc[et][r] = 0.f;
    float m = -__builtin_inff(), lsum = 0.f;

    const u64* mrow = msk + (size_t)(qr0 + l31) * NW + kvs * NIT;

    const int kr = tid >> 3, kc = (tid & 7) * 16;
    const int hr = tid >> 2, hc = (tid & 3) * 16;
    const int ksw = (kr & 7) << 4, hsw = (hr & 7) << 4;
    bf16x8 kg[2], hg[2];

    auto LOADG = [&](int c0) {
        kg[0] = *reinterpret_cast<const bf16x8*>(kb + (size_t)(c0 + kr) * EE + kc);
        kg[1] = *reinterpret_cast<const bf16x8*>(kb + (size_t)(c0 + kr) * EE + kc + 8);
        hg[0] = *reinterpret_cast<const bf16x8*>(hT + (size_t)hr * NN + c0 + hc);
        hg[1] = *reinterpret_cast<const bf16x8*>(hT + (size_t)hr * NN + c0 + hc + 8);
    };
    auto WLDS = [&](int b) {
        char* kB = smem + b * 16384;
        *reinterpret_cast<bf16x8*>(kB + kr * 256 + ((kc * 2) ^ ksw))      = kg[0];
        *reinterpret_cast<bf16x8*>(kB + kr * 256 + ((kc * 2 + 16) ^ ksw)) = kg[1];
        char* hB = smem + 32768 + b * 16384;
        *reinterpret_cast<bf16x8*>(hB + hr * 128 + ((hc * 2) ^ hsw))      = hg[0];
        *reinterpret_cast<bf16x8*>(hB + hr * 128 + ((hc * 2 + 16) ^ hsw)) = hg[1];
    };

    LOADG(kv0);
    WLDS(0);
    __syncthreads();

    const int rsw = (l31 & 7) << 4;

    for (int cc = 0; cc < NIT; ++cc) {
        if (cc + 1 < NIT) LOADG(kv0 + (cc + 1) * 64);
        const char* kB = smem + (cc & 1) * 16384;
        const char* hB = smem + 32768 + (cc & 1) * 16384;
        const u64 mw = mrow[cc];

        f32x16 sv0, sv1;
        #pragma unroll
        for (int r = 0; r < 16; ++r) { sv0[r] = 0.f; sv1[r] = 0.f; }
        #pragma unroll
        for (int s = 0; s < 8; ++s) {
            bf16x8 a0 = *reinterpret_cast<const bf16x8*>(
                kB + l31 * 256 + ((s * 32 + hf * 16) ^ rsw));
            sv0 = __builtin_amdgcn_mfma_f32_32x32x16_bf16(a0, qf[s], sv0, 0, 0, 0);
            bf16x8 a1 = *reinterpret_cast<const bf16x8*>(
                kB + (32 + l31) * 256 + ((s * 32 + hf * 16) ^ rsw));
            sv1 = __builtin_amdgcn_mfma_f32_32x32x16_bf16(a1, qf[s], sv1, 0, 0, 0);
        }

        float pv[32];
        float rm = -__builtin_inff();
        #pragma unroll
        for (int r = 0; r < 16; ++r) {
            int k0i = (r & 3) + 8 * (r >> 2) + 4 * hf;
            float v0 = ((mw >> k0i) & 1ull) ? sv0[r] : -__builtin_inff();
            float v1 = ((mw >> (k0i + 32)) & 1ull) ? sv1[r] : -__builtin_inff();
            pv[r] = v0; pv[16 + r] = v1;
            rm = fmaxf(rm, fmaxf(v0, v1));
        }
        rm = fmaxf(rm, __shfl_xor(rm, 32));
        const float mn2 = fmaxf(m, rm);
        const float alpha = (mn2 == m) ? 1.f : __expf(m - mn2);
        const bool noresc = __all(mn2 == m);   // wave-uniform: max didn't grow
        m = mn2;

        float rs = 0.f;
        const bool dead = (mn2 == -__builtin_inff());
        #pragma unroll
        for (int i = 0; i < 32; ++i) {
            float p = dead ? 0.f : __expf(pv[i] - mn2);
            pv[i] = p;
            rs += p;
        }
        rs += __shfl_xor(rs, 32);
        lsum = lsum * alpha + rs;

        u32 w[8][2];
        #pragma unroll
        for (int qd = 0; qd < 8; ++qd) {
            int base = 16 * (qd >> 2) + 4 * (qd & 3);
            w[qd][0] = cvtpk_bf16(pv[base], pv[base + 1]);
            w[qd][1] = cvtpk_bf16(pv[base + 2], pv[base + 3]);
        }

        if (!noresc) {   // skip exact-1.0 rescale (64 mults) when wave-uniform
            #pragma unroll
            for (int et = 0; et < 4; ++et)
                #pragma unroll
                for (int r = 0; r < 16; ++r) acc[et][r] *= alpha;
        }

        #pragma unroll
        for (int s = 0; s < 4; ++s) {
            u32 s0 = hf == 0 ? w[2 * s + 1][0] : w[2 * s][0];
            u32 s1 = hf == 0 ? w[2 * s + 1][1] : w[2 * s][1];
            u32 r0 = __shfl_xor(s0, 32);
            u32 r1 = __shfl_xor(s1, 32);
            union { u32 u[4]; bf16x8 v; } b2;
            b2.u[0] = hf == 0 ? w[2 * s][0] : r0;
            b2.u[1] = hf == 0 ? w[2 * s][1] : r1;
            b2.u[2] = hf == 0 ? r0 : w[2 * s + 1][0];
            b2.u[3] = hf == 0 ? r1 : w[2 * s + 1][1];
            #pragma unroll
            for (int et = 0; et < 4; ++et) {
                bf16x8 a2 = *reinterpret_cast<const bf16x8*>(
                    hB + (32 * et + l31) * 128 + ((s * 32 + hf * 16) ^ rsw));
                acc[et] = __builtin_amdgcn_mfma_f32_32x32x16_bf16(a2, b2.v, acc[et], 0, 0, 0);
            }
        }
        if (cc + 1 < NIT) WLDS((cc + 1) & 1);
        __syncthreads();
    }

    const size_t pbase = (size_t)kvs * NN + qr0;
    #pragma unroll
    for (int et = 0; et < 4; ++et)
        #pragma unroll
        for (int r = 0; r < 16; ++r) {
            int e = 32 * et + (r & 3) + 8 * (r >> 2) + 4 * hf;
            pacc[(pbase + l31) * EE + e] = (_Float16)acc[et][r];
        }
    if (hf == 0) {
        pm[pbase + l31] = m;
        pl[pbase + l31] = lsum;
    }
}

// ---------------------------------------------------------------------------
// Kernel 3 (fused): combine the 8 KV-split partials inline, then
// out = relu(agg@wh1+bh1)@wh2 + bh2.
// ---------------------------------------------------------------------------
__global__ __launch_bounds__(128) void k_head(
    const _Float16* __restrict__ pacc, const float* __restrict__ pm,
    const float* __restrict__ pl,
    const float* __restrict__ wh1, const float* __restrict__ bh1,
    const float* __restrict__ wh2, const float* __restrict__ bh2,
    float* __restrict__ out)
{
    __shared__ float ag[16][EE + 1];
    __shared__ float h2[16][EE + 1];
    __shared__ float eps[16][NKVS];    // per-row ep[p]/L
    const int t  = threadIdx.x;
    const int ec = (t & 15) * 8;
    const int ra = (t >> 4) * 2, rb = ra + 1;
    const int r0b = blockIdx.x * 16;

    if (t < 16) {
        const int row = r0b + t;
        float mp[NKVS], M = -__builtin_inff();
        #pragma unroll
        for (int p = 0; p < NKVS; ++p) { mp[p] = pm[(size_t)p * NN + row]; M = fmaxf(M, mp[p]); }
        float ep[NKVS], L = 0.f;
        #pragma unroll
        for (int p = 0; p < NKVS; ++p) { ep[p] = __expf(mp[p] - M); L += pl[(size_t)p * NN + row] * ep[p]; }
        const float invL = 1.f / L;
        #pragma unroll
        for (int p = 0; p < NKVS; ++p) eps[t][p] = ep[p] * invL;
    }
    __syncthreads();

    #pragma unroll
    for (int r = 0; r < 16; ++r) {
        float s = 0.f;
        #pragma unroll
        for (int p = 0; p < NKVS; ++p)
            s += (float)pacc[((size_t)p * NN + r0b + r) * EE + t] * eps[r][p];
        ag[r][t] = s;
    }
    __syncthreads();

    {
        float a0[8], a1[8];
        #pragma unroll
        for (int j = 0; j < 8; ++j) { float b = bh1[ec + j]; a0[j] = b; a1[j] = b; }
        for (int s = 0; s < EE; ++s) {
            float x0 = ag[ra][s], x1 = ag[rb][s];
            const float* wrow = wh1 + s * EE + ec;
            #pragma unroll
            for (int j = 0; j < 8; ++j) { float w = wrow[j]; a0[j] = fmaf(x0, w, a0[j]); a1[j] = fmaf(x1, w, a1[j]); }
        }
        #pragma unroll
        for (int j = 0; j < 8; ++j) { h2[ra][ec + j] = fmaxf(a0[j], 0.f); h2[rb][ec + j] = fmaxf(a1[j], 0.f); }
    }
    __syncthreads();
    const int r = t >> 3, a = t & 7;
    float o = bh2[a];
    for (int s = 0; s < EE; ++s) o = fmaf(h2[r][s], wh2[s * AA + a], o);
    out[(size_t)(r0b + r) * AA + a] = o;
}

// ---------------------------------------------------------------------------
extern "C" void kernel_launch(void* const* d_in, const int* in_sizes, int n_in,
                              void* d_out, int out_size, void* d_ws, size_t ws_size,
                              hipStream_t stream)
{
    (void)in_sizes; (void)n_in; (void)out_size; (void)ws_size;
    const float* state = (const float*)d_in[0];
    const int*   adj   = (const int*)d_in[1];
    const float* w1  = (const float*)d_in[2];
    const float* b1  = (const float*)d_in[3];
    const float* w2  = (const float*)d_in[4];
    const float* b2  = (const float*)d_in[5];
    const float* wq  = (const float*)d_in[6];
    const float* wk  = (const float*)d_in[7];
    const float* wh1 = (const float*)d_in[8];
    const float* bh1 = (const float*)d_in[9];
    const float* wh2 = (const float*)d_in[10];
    const float* bh2 = (const float*)d_in[11];
    float* out = (float*)d_out;

    char* ws = (char*)d_ws;
    const size_t MB = 1024 * 1024;
    u16*      qb   = (u16*)ws;                       //  0..2 MB
    u16*      kb   = (u16*)(ws + 2 * MB);            //  2..4 MB
    u16*      hT   = (u16*)(ws + 4 * MB);            //  4..6 MB
    u64*      msk  = (u64*)(ws + 10 * MB);           // 10..18 MB
    _Float16* pacc = (_Float16*)(ws + 18 * MB);      // 18..34 MB
    float*    pm   = (float*)(ws + 34 * MB);         // 34..34.25 MB
    float*    pl   = (float*)(ws + 34 * MB + 256 * 1024); // 34.25..34.5 MB

    k_mlp    <<<NN / 16, 128, 0, stream>>>(state, w1, b1, w2, b2, wq, wk, qb, kb, hT);
    k_adjmask<<<2048, 256, 0, stream>>>(adj, msk);
    k_attn   <<<(NN / QTILE) * NKVS, 512, 0, stream>>>(qb, kb, hT, msk, pacc, pm, pl);
    k_head   <<<NN / 16, 128, 0, stream>>>(pacc, pm, pl, wh1, bh1, wh2, bh2, out);
}